// Round 1
// baseline (828.698 us; speedup 1.0000x reference)
//
#include <hip/hip_runtime.h>
#include <hip/hip_bf16.h>

// Problem constants (fixed by reference)
#define T_TOK   13294
#define BS_     2
#define M_ROWS  (BS_ * T_TOK)   // 26588
#define EMBED_  256
#define HID_    1024

// ---------------------------------------------------------------------------
// LayerNorm (one block per row, 256 threads = 1 elem/thread)
// ADDPOS: also emit q = ln(x) + pos
// ---------------------------------------------------------------------------
template <bool ADDPOS>
__global__ __launch_bounds__(256) void ln_kernel(
    const float* __restrict__ x, const float* __restrict__ pos,
    const float* __restrict__ g, const float* __restrict__ bta,
    float* __restrict__ y, float* __restrict__ q) {
  const int r = blockIdx.x;
  const int tid = threadIdx.x;
  const size_t base = (size_t)r * 256 + tid;
  float v = x[base];

  // mean
  float s = v;
  #pragma unroll
  for (int m = 32; m; m >>= 1) s += __shfl_xor(s, m, 64);
  __shared__ float red[4];
  const int wid = tid >> 6;
  if ((tid & 63) == 0) red[wid] = s;
  __syncthreads();
  const float mean = (red[0] + red[1] + red[2] + red[3]) * (1.0f / 256.0f);

  const float d = v - mean;
  float s2 = d * d;
  #pragma unroll
  for (int m = 32; m; m >>= 1) s2 += __shfl_xor(s2, m, 64);
  __syncthreads();                    // WAR on red[]
  if ((tid & 63) == 0) red[wid] = s2;
  __syncthreads();
  const float var = (red[0] + red[1] + red[2] + red[3]) * (1.0f / 256.0f);

  const float out = d * rsqrtf(var + 1e-5f) * g[tid] + bta[tid];
  y[base] = out;
  if (ADDPOS) q[base] = out + pos[base];
}

// ---------------------------------------------------------------------------
// Generic fp32 tiled GEMM: C = A[M,K] @ W[K,N] + bias  (+epilogue)
// EPI: 0 = bias, 1 = bias+relu, 2 = bias + residual R
// BM=BN=64, BK=16, 256 threads, 4x4 per thread
// ---------------------------------------------------------------------------
template <int EPI>
__global__ __launch_bounds__(256) void gemm_kernel(
    const float* __restrict__ A, const float* __restrict__ W,
    const float* __restrict__ bias, const float* __restrict__ R,
    float* __restrict__ C, int M, int N, int K) {
  __shared__ float As[16][68];   // [k][row] transposed, padded
  __shared__ float Bs[16][64];   // [k][col]

  const int tid = threadIdx.x;
  const int row0 = blockIdx.x * 64;
  const int col0 = blockIdx.y * 64;
  const int tx = tid & 15, ty = tid >> 4;

  float acc[4][4] = {};

  const int ar = tid >> 2;            // 0..63  (A tile row)
  const int ac = (tid & 3) * 4;       // 0,4,8,12 (A tile k)
  const int wr = tid >> 4;            // 0..15  (W tile k)
  const int wc = (tid & 15) * 4;      // 0..60  (W tile col)

  for (int k0 = 0; k0 < K; k0 += 16) {
    // A tile (64 x 16), M-guarded
    const int gr = row0 + ar;
    float4 a4 = make_float4(0.f, 0.f, 0.f, 0.f);
    if (gr < M) a4 = *reinterpret_cast<const float4*>(&A[(size_t)gr * K + k0 + ac]);
    As[ac + 0][ar] = a4.x; As[ac + 1][ar] = a4.y;
    As[ac + 2][ar] = a4.z; As[ac + 3][ar] = a4.w;
    // W tile (16 x 64)
    float4 w4 = *reinterpret_cast<const float4*>(&W[(size_t)(k0 + wr) * N + col0 + wc]);
    *reinterpret_cast<float4*>(&Bs[wr][wc]) = w4;
    __syncthreads();

    #pragma unroll
    for (int kk = 0; kk < 16; ++kk) {
      const float4 a = *reinterpret_cast<const float4*>(&As[kk][ty * 4]);
      const float4 b = *reinterpret_cast<const float4*>(&Bs[kk][tx * 4]);
      const float av[4] = {a.x, a.y, a.z, a.w};
      const float bv[4] = {b.x, b.y, b.z, b.w};
      #pragma unroll
      for (int i = 0; i < 4; ++i)
        #pragma unroll
        for (int j = 0; j < 4; ++j)
          acc[i][j] = fmaf(av[i], bv[j], acc[i][j]);
    }
    __syncthreads();
  }

  const int n0 = col0 + tx * 4;
  const float4 b4 = *reinterpret_cast<const float4*>(&bias[n0]);
  #pragma unroll
  for (int i = 0; i < 4; ++i) {
    const int m = row0 + ty * 4 + i;
    if (m >= M) continue;
    float4 o;
    o.x = acc[i][0] + b4.x; o.y = acc[i][1] + b4.y;
    o.z = acc[i][2] + b4.z; o.w = acc[i][3] + b4.w;
    if (EPI == 1) {
      o.x = fmaxf(o.x, 0.f); o.y = fmaxf(o.y, 0.f);
      o.z = fmaxf(o.z, 0.f); o.w = fmaxf(o.w, 0.f);
    }
    if (EPI == 2) {
      const float4 r4 = *reinterpret_cast<const float4*>(&R[(size_t)m * N + n0]);
      o.x += r4.x; o.y += r4.y; o.z += r4.z; o.w += r4.w;
    }
    *reinterpret_cast<float4*>(&C[(size_t)m * N + n0]) = o;
  }
}

// ---------------------------------------------------------------------------
// Fused softmax + multi-scale deformable sampling.
// One block per (b,t): 256 threads = 8 heads x 32 channels.
// ---------------------------------------------------------------------------
__global__ __launch_bounds__(256) void msda_kernel(
    const float* __restrict__ v, const float* __restrict__ offb,
    const float* __restrict__ awl, const float* __restrict__ ref,
    float* __restrict__ outb) {
  const int r = blockIdx.x;                 // row = b*T + t
  const int b = r / T_TOK;
  const int tid = threadIdx.x;

  __shared__ float s_off[256];
  __shared__ float s_aw[128];
  __shared__ float s_ref[8];

  s_off[tid] = offb[(size_t)r * 256 + tid];
  if (tid < 128) {
    const float lg = awl[(size_t)r * 128 + tid];
    float mx = lg;
    #pragma unroll
    for (int m = 8; m; m >>= 1) mx = fmaxf(mx, __shfl_xor(mx, m, 16));
    const float e = expf(lg - mx);
    float ssum = e;
    #pragma unroll
    for (int m = 8; m; m >>= 1) ssum += __shfl_xor(ssum, m, 16);
    s_aw[tid] = e / ssum;
  }
  if (tid < 8) s_ref[tid] = ref[(size_t)r * 8 + tid];
  __syncthreads();

  const int h = tid >> 5, d = tid & 31;
  const int HH[4] = {100, 50, 25, 13};
  const int WW[4] = {100, 50, 25, 13};
  const int SS[4] = {0, 10000, 12500, 13125};

  float acc = 0.f;
  #pragma unroll
  for (int l = 0; l < 4; ++l) {
    const float Wl = (float)WW[l], Hl = (float)HH[l];
    const float rx = s_ref[l * 2 + 0], ry = s_ref[l * 2 + 1];
    #pragma unroll
    for (int p = 0; p < 4; ++p) {
      const float ox = s_off[h * 32 + l * 8 + p * 2 + 0];
      const float oy = s_off[h * 32 + l * 8 + p * 2 + 1];
      const float x = rx * Wl + ox - 0.5f;
      const float y = ry * Hl + oy - 0.5f;
      const float x0f = floorf(x), y0f = floorf(y);
      const int x0 = (int)x0f, y0 = (int)y0f;
      const float wx1 = x - x0f, wy1 = y - y0f;
      const float wx0 = 1.f - wx1, wy0 = 1.f - wy1;
      const float aw = s_aw[h * 16 + l * 4 + p];

      float bil = 0.f;
      #pragma unroll
      for (int cy = 0; cy < 2; ++cy) {
        const int yy = y0 + cy;
        const float wy = cy ? wy1 : wy0;
        const bool vy = (yy >= 0) && (yy < HH[l]);
        const int yc = min(max(yy, 0), HH[l] - 1);
        #pragma unroll
        for (int cx = 0; cx < 2; ++cx) {
          const int xx = x0 + cx;
          const float wx = cx ? wx1 : wx0;
          const bool vx = (xx >= 0) && (xx < WW[l]);
          const int xc = min(max(xx, 0), WW[l] - 1);
          float gv = 0.f;
          if (vx && vy)
            gv = v[(((size_t)b * T_TOK + SS[l] + yc * WW[l] + xc) * 256) + h * 32 + d];
          bil = fmaf(wy * wx, gv, bil);
        }
      }
      acc = fmaf(aw, bil, acc);
    }
  }
  outb[(size_t)r * 256 + tid] = acc;
}

// ---------------------------------------------------------------------------
// Host launcher
// ---------------------------------------------------------------------------
extern "C" void kernel_launch(void* const* d_in, const int* in_sizes, int n_in,
                              void* d_out, int out_size, void* d_ws, size_t ws_size,
                              hipStream_t stream) {
  const float* src     = (const float*)d_in[0];
  const float* pos     = (const float*)d_in[1];
  const float* ref     = (const float*)d_in[2];
  // d_in[3] spatial_shapes, d_in[4] level_start_index: compile-time constants
  const float* ln1_g   = (const float*)d_in[5];
  const float* ln1_b   = (const float*)d_in[6];
  const float* ln2_g   = (const float*)d_in[7];
  const float* ln2_b   = (const float*)d_in[8];
  const float* W_value = (const float*)d_in[9];
  const float* b_value = (const float*)d_in[10];
  const float* W_off   = (const float*)d_in[11];
  const float* b_off   = (const float*)d_in[12];
  const float* W_attn  = (const float*)d_in[13];
  const float* b_attn  = (const float*)d_in[14];
  const float* W_out   = (const float*)d_in[15];
  const float* b_out   = (const float*)d_in[16];
  const float* W_ffn1  = (const float*)d_in[17];
  const float* b_ffn1  = (const float*)d_in[18];
  const float* W_ffn2  = (const float*)d_in[19];
  const float* b_ffn2  = (const float*)d_in[20];
  float* out = (float*)d_out;
  float* ws  = (float*)d_ws;

  const int M = M_ROWS;
  const size_t n256 = (size_t)M * 256;

  // Workspace layout (fp32), 231.4 MB total, buffers reused across phases:
  float* src_n = ws;                                   // later: src1
  float* qbuf  = ws + n256;                            // later: attn_mid
  float* vbuf  = ws + 2 * n256;                        // later: src_n2
  float* offb  = ws + 3 * n256;
  float* awbuf = ws + 4 * n256;                        // M*128
  float* hid   = ws + 4 * n256 + (size_t)M * 128;      // M*1024

  // 1. LN1 + q = ln(src) + pos
  ln_kernel<true><<<M, 256, 0, stream>>>(src, pos, ln1_g, ln1_b, src_n, qbuf);

  const dim3 blk(256);
  const dim3 g256((M + 63) / 64, 256 / 64);
  const dim3 g128((M + 63) / 64, 128 / 64);
  const dim3 g1024((M + 63) / 64, 1024 / 64);

  // 2. Projections
  gemm_kernel<0><<<g256, blk, 0, stream>>>(src_n, W_value, b_value, nullptr, vbuf, M, 256, 256);
  gemm_kernel<0><<<g256, blk, 0, stream>>>(qbuf, W_off, b_off, nullptr, offb, M, 256, 256);
  gemm_kernel<0><<<g128, blk, 0, stream>>>(qbuf, W_attn, b_attn, nullptr, awbuf, M, 128, 256);

  // 3. softmax + deformable bilinear sampling -> attn_mid (reuses q buffer)
  msda_kernel<<<M, 256, 0, stream>>>(vbuf, offb, awbuf, ref, qbuf);

  // 4. out-proj + residual: src1 = src + attn_mid @ W_out + b_out (into src_n buf)
  gemm_kernel<2><<<g256, blk, 0, stream>>>(qbuf, W_out, b_out, src, src_n, M, 256, 256);

  // 5. LN2 -> src_n2 (reuses v buffer)
  ln_kernel<false><<<M, 256, 0, stream>>>(src_n, nullptr, ln2_g, ln2_b, vbuf, nullptr);

  // 6. FFN
  gemm_kernel<1><<<g1024, blk, 0, stream>>>(vbuf, W_ffn1, b_ffn1, nullptr, hid, M, 1024, 256);
  gemm_kernel<2><<<g256, blk, 0, stream>>>(hid, W_ffn2, b_ffn2, src_n, out, M, 256, 1024);
}

// Round 2
// 385.870 us; speedup vs baseline: 2.1476x; 2.1476x over previous
//
#include <hip/hip_runtime.h>
#include <hip/hip_bf16.h>

#define T_TOK   13294
#define BS_     2
#define M_ROWS  (BS_ * T_TOK)   // 26588
#define EMBED_  256
#define HID_    1024

typedef __attribute__((ext_vector_type(8))) short short8;
typedef __attribute__((ext_vector_type(4))) float f32x4;

__device__ __forceinline__ unsigned short f2bf(float f) {
  __hip_bfloat16 h = __float2bfloat16(f);
  return *reinterpret_cast<unsigned short*>(&h);
}
__device__ __forceinline__ float bf2f(unsigned short u) {
  unsigned int x = ((unsigned int)u) << 16;
  return __uint_as_float(x);
}

// ---------------------------------------------------------------------------
// Weight transpose + bf16 cast: W [K,N] f32 -> Wt [N,K] bf16
// ---------------------------------------------------------------------------
__global__ __launch_bounds__(256) void transpose_bf16_kernel(
    const float* __restrict__ W, unsigned short* __restrict__ Wt, int K, int N) {
  __shared__ float t[32][33];
  const int k0 = blockIdx.x * 32, n0 = blockIdx.y * 32;
  const int tx = threadIdx.x, ty = threadIdx.y;   // 32 x 8
  #pragma unroll
  for (int i = 0; i < 32; i += 8)
    t[ty + i][tx] = W[(size_t)(k0 + ty + i) * N + n0 + tx];
  __syncthreads();
  #pragma unroll
  for (int i = 0; i < 32; i += 8)
    Wt[(size_t)(n0 + ty + i) * K + k0 + tx] = f2bf(t[tx][ty + i]);
}

// ---------------------------------------------------------------------------
// LayerNorm -> bf16 (one block per row). ADDPOS: also q = ln(x)+pos (bf16)
// ---------------------------------------------------------------------------
template <bool ADDPOS>
__global__ __launch_bounds__(256) void ln_kernel(
    const float* __restrict__ x, const float* __restrict__ pos,
    const float* __restrict__ g, const float* __restrict__ bta,
    unsigned short* __restrict__ y, unsigned short* __restrict__ q) {
  const int r = blockIdx.x;
  const int tid = threadIdx.x;
  const size_t base = (size_t)r * 256 + tid;
  float v = x[base];

  float s = v;
  #pragma unroll
  for (int m = 32; m; m >>= 1) s += __shfl_xor(s, m, 64);
  __shared__ float red[4];
  const int wid = tid >> 6;
  if ((tid & 63) == 0) red[wid] = s;
  __syncthreads();
  const float mean = (red[0] + red[1] + red[2] + red[3]) * (1.0f / 256.0f);

  const float d = v - mean;
  float s2 = d * d;
  #pragma unroll
  for (int m = 32; m; m >>= 1) s2 += __shfl_xor(s2, m, 64);
  __syncthreads();
  if ((tid & 63) == 0) red[wid] = s2;
  __syncthreads();
  const float var = (red[0] + red[1] + red[2] + red[3]) * (1.0f / 256.0f);

  const float out = d * rsqrtf(var + 1e-5f) * g[tid] + bta[tid];
  y[base] = f2bf(out);
  if (ADDPOS) q[base] = f2bf(out + pos[base]);
}

// ---------------------------------------------------------------------------
// MFMA bf16 GEMM: C = A[M,K](bf16) @ Wt[N,K]^T(bf16) + bias
// 128x128 tile, BK=32, 256 threads (4 waves 2x2), global_load_lds staging.
// EPI: 0=bias, 1=bias+relu, 2=bias+residual R(f32). OUTBF: bf16 vs f32 out.
// ---------------------------------------------------------------------------
template <int EPI, bool OUTBF>
__global__ __launch_bounds__(256) void mgemm(
    const unsigned short* __restrict__ A, const unsigned short* __restrict__ Wt,
    const float* __restrict__ bias, const float* __restrict__ R,
    void* __restrict__ Cv, int M, int N, int K) {
  __shared__ unsigned short As[128 * 32];
  __shared__ unsigned short Bs[128 * 32];

  const int tid = threadIdx.x;
  const int lane = tid & 63;
  const int w = tid >> 6;
  const int wm = w >> 1, wn = w & 1;
  const int row0 = blockIdx.x * 128;
  const int col0 = blockIdx.y * 128;

  f32x4 acc[4][4] = {};

  const int frow = lane & 15;
  const int fk = (lane >> 4) * 8;

  for (int k0 = 0; k0 < K; k0 += 32) {
    // stage A (128x32) and B (128x32), 2 chunks each of 256 lanes x 16B
    #pragma unroll
    for (int i = 0; i < 2; ++i) {
      const int chunk = i * 256 + tid;     // 0..511
      const int rrow = chunk >> 2;         // 0..127
      const int kg = chunk & 3;
      int ga_row = row0 + rrow; if (ga_row >= M) ga_row = M - 1;   // clamp (no OOB)
      const unsigned short* gA = A + (size_t)ga_row * K + k0 + kg * 8;
      __builtin_amdgcn_global_load_lds(
          (const __attribute__((address_space(1))) void*)gA,
          (__attribute__((address_space(3))) void*)&As[chunk * 8], 16, 0, 0);
      const unsigned short* gB = Wt + (size_t)(col0 + rrow) * K + k0 + kg * 8;
      __builtin_amdgcn_global_load_lds(
          (const __attribute__((address_space(1))) void*)gB,
          (__attribute__((address_space(3))) void*)&Bs[chunk * 8], 16, 0, 0);
    }
    __syncthreads();

    short8 a[4], b[4];
    #pragma unroll
    for (int mi = 0; mi < 4; ++mi)
      a[mi] = *reinterpret_cast<const short8*>(&As[(wm * 64 + mi * 16 + frow) * 32 + fk]);
    #pragma unroll
    for (int ni = 0; ni < 4; ++ni)
      b[ni] = *reinterpret_cast<const short8*>(&Bs[(wn * 64 + ni * 16 + frow) * 32 + fk]);
    #pragma unroll
    for (int mi = 0; mi < 4; ++mi)
      #pragma unroll
      for (int ni = 0; ni < 4; ++ni)
        acc[mi][ni] = __builtin_amdgcn_mfma_f32_16x16x32_bf16(a[mi], b[ni], acc[mi][ni], 0, 0, 0);
    __syncthreads();
  }

  // epilogue: C/D layout col=lane&15, row=(lane>>4)*4+r
  const int cl = lane & 15;
  const int rb = (lane >> 4) * 4;
  #pragma unroll
  for (int ni = 0; ni < 4; ++ni) {
    const int gc = col0 + wn * 64 + ni * 16 + cl;
    const float bv = bias[gc];
    #pragma unroll
    for (int mi = 0; mi < 4; ++mi) {
      const int gr0 = row0 + wm * 64 + mi * 16 + rb;
      #pragma unroll
      for (int r = 0; r < 4; ++r) {
        const int gr = gr0 + r;
        if (gr >= M) continue;
        float val = acc[mi][ni][r] + bv;
        if (EPI == 1) val = fmaxf(val, 0.f);
        if (EPI == 2) val += R[(size_t)gr * N + gc];
        if (OUTBF) ((unsigned short*)Cv)[(size_t)gr * N + gc] = f2bf(val);
        else       ((float*)Cv)[(size_t)gr * N + gc] = val;
      }
    }
  }
}

// ---------------------------------------------------------------------------
// Fused softmax + deformable sampling. 4 tokens/block, 256 threads.
// Thread = (token t=tid>>6, head h=(tid&63)>>3, 4-channel group d4=tid&7).
// v is bf16 [M,256]; out bf16 [M,256].
// ---------------------------------------------------------------------------
__global__ __launch_bounds__(256) void msda_kernel(
    const unsigned short* __restrict__ v, const float* __restrict__ offb,
    const float* __restrict__ awl, const float* __restrict__ ref,
    unsigned short* __restrict__ outb) {
  const int r0 = blockIdx.x * 4;
  const int tid = threadIdx.x;

  __shared__ float s_off[4 * 256];
  __shared__ float s_aw[4 * 128];
  __shared__ float s_ref[4 * 8];

  #pragma unroll
  for (int i = 0; i < 4; ++i)
    s_off[i * 256 + tid] = offb[(size_t)(r0 + i) * 256 + tid];
  if (tid < 32) s_ref[tid] = ref[(size_t)r0 * 8 + tid];

  // softmax: 32 (token,head) pairs, 8 threads each, 2 logits/thread
  {
    const int pair = tid >> 3;          // 0..31: tok = pair>>3, h = pair&7
    const int j = tid & 7;
    const int tok = pair >> 3, h = pair & 7;
    const size_t base = (size_t)(r0 + tok) * 128 + h * 16 + j * 2;
    const float l0 = awl[base], l1 = awl[base + 1];
    float mx = fmaxf(l0, l1);
    #pragma unroll
    for (int m = 1; m < 8; m <<= 1) mx = fmaxf(mx, __shfl_xor(mx, m, 64));
    const float e0 = expf(l0 - mx), e1 = expf(l1 - mx);
    float ss = e0 + e1;
    #pragma unroll
    for (int m = 1; m < 8; m <<= 1) ss += __shfl_xor(ss, m, 64);
    const float inv = 1.0f / ss;
    s_aw[tok * 128 + h * 16 + j * 2] = e0 * inv;
    s_aw[tok * 128 + h * 16 + j * 2 + 1] = e1 * inv;
  }
  __syncthreads();

  const int t = tid >> 6;
  const int lane = tid & 63;
  const int h = lane >> 3, d4 = lane & 7;
  const int r = r0 + t;
  const int b = r / T_TOK;

  const int HH[4] = {100, 50, 25, 13};
  const int WW[4] = {100, 50, 25, 13};
  const int SS[4] = {0, 10000, 12500, 13125};

  float acc0 = 0.f, acc1 = 0.f, acc2 = 0.f, acc3 = 0.f;
  #pragma unroll
  for (int l = 0; l < 4; ++l) {
    const float Wl = (float)WW[l], Hl = (float)HH[l];
    const float rx = s_ref[t * 8 + l * 2], ry = s_ref[t * 8 + l * 2 + 1];
    #pragma unroll
    for (int p = 0; p < 4; ++p) {
      const float ox = s_off[t * 256 + h * 32 + l * 8 + p * 2];
      const float oy = s_off[t * 256 + h * 32 + l * 8 + p * 2 + 1];
      const float x = rx * Wl + ox - 0.5f;
      const float y = ry * Hl + oy - 0.5f;
      const float x0f = floorf(x), y0f = floorf(y);
      const int x0 = (int)x0f, y0 = (int)y0f;
      const float wx1 = x - x0f, wy1 = y - y0f;
      const float wx0 = 1.f - wx1, wy0 = 1.f - wy1;
      const float aw = s_aw[t * 128 + h * 16 + l * 4 + p];

      float b0 = 0.f, b1 = 0.f, b2 = 0.f, b3 = 0.f;
      #pragma unroll
      for (int cy = 0; cy < 2; ++cy) {
        const int yy = y0 + cy;
        const float wy = cy ? wy1 : wy0;
        const bool vy = (yy >= 0) && (yy < HH[l]);
        const int yc = min(max(yy, 0), HH[l] - 1);
        #pragma unroll
        for (int cx = 0; cx < 2; ++cx) {
          const int xx = x0 + cx;
          const float wx = cx ? wx1 : wx0;
          const bool vx = (xx >= 0) && (xx < WW[l]);
          const int xc = min(max(xx, 0), WW[l] - 1);
          if (vx && vy) {
            const size_t base =
                ((size_t)(b * T_TOK + SS[l] + yc * WW[l] + xc)) * 256 + h * 32 + d4 * 4;
            const uint2 u = *reinterpret_cast<const uint2*>(&v[base]);
            const float ww = wy * wx;
            b0 = fmaf(ww, bf2f((unsigned short)(u.x & 0xffff)), b0);
            b1 = fmaf(ww, bf2f((unsigned short)(u.x >> 16)), b1);
            b2 = fmaf(ww, bf2f((unsigned short)(u.y & 0xffff)), b2);
            b3 = fmaf(ww, bf2f((unsigned short)(u.y >> 16)), b3);
          }
        }
      }
      acc0 = fmaf(aw, b0, acc0); acc1 = fmaf(aw, b1, acc1);
      acc2 = fmaf(aw, b2, acc2); acc3 = fmaf(aw, b3, acc3);
    }
  }
  const size_t ob = (size_t)r * 256 + h * 32 + d4 * 4;
  ushort4 o;
  o.x = f2bf(acc0); o.y = f2bf(acc1); o.z = f2bf(acc2); o.w = f2bf(acc3);
  *reinterpret_cast<ushort4*>(&outb[ob]) = o;
}

// ---------------------------------------------------------------------------
// Host launcher
// ---------------------------------------------------------------------------
extern "C" void kernel_launch(void* const* d_in, const int* in_sizes, int n_in,
                              void* d_out, int out_size, void* d_ws, size_t ws_size,
                              hipStream_t stream) {
  const float* src     = (const float*)d_in[0];
  const float* pos     = (const float*)d_in[1];
  const float* ref     = (const float*)d_in[2];
  const float* ln1_g   = (const float*)d_in[5];
  const float* ln1_b   = (const float*)d_in[6];
  const float* ln2_g   = (const float*)d_in[7];
  const float* ln2_b   = (const float*)d_in[8];
  const float* W_value = (const float*)d_in[9];
  const float* b_value = (const float*)d_in[10];
  const float* W_off   = (const float*)d_in[11];
  const float* b_off   = (const float*)d_in[12];
  const float* W_attn  = (const float*)d_in[13];
  const float* b_attn  = (const float*)d_in[14];
  const float* W_out   = (const float*)d_in[15];
  const float* b_out   = (const float*)d_in[16];
  const float* W_ffn1  = (const float*)d_in[17];
  const float* b_ffn1  = (const float*)d_in[18];
  const float* W_ffn2  = (const float*)d_in[19];
  const float* b_ffn2  = (const float*)d_in[20];
  float* out = (float*)d_out;

  const int M = M_ROWS;
  const size_t n256 = (size_t)M * 256;

  // workspace layout
  unsigned short* src_n_bf = (unsigned short*)d_ws;
  unsigned short* q_bf     = src_n_bf + n256;
  unsigned short* v_bf     = q_bf + n256;
  unsigned short* attn_bf  = v_bf + n256;
  unsigned short* sn2_bf   = attn_bf + n256;
  unsigned short* hid_bf   = sn2_bf + n256;                  // M*1024
  float* offb  = (float*)(hid_bf + (size_t)M * 1024);
  float* awbuf = offb + n256;
  float* src1  = awbuf + (size_t)M * 128;
  unsigned short* wt_val  = (unsigned short*)(src1 + n256);
  unsigned short* wt_off  = wt_val + 256 * 256;
  unsigned short* wt_attn = wt_off + 256 * 256;
  unsigned short* wt_out  = wt_attn + 128 * 256;
  unsigned short* wt_ffn1 = wt_out + 256 * 256;
  unsigned short* wt_ffn2 = wt_ffn1 + 1024 * 256;

  const dim3 tb(32, 8);
  transpose_bf16_kernel<<<dim3(256 / 32, 256 / 32), tb, 0, stream>>>(W_value, wt_val, 256, 256);
  transpose_bf16_kernel<<<dim3(256 / 32, 256 / 32), tb, 0, stream>>>(W_off, wt_off, 256, 256);
  transpose_bf16_kernel<<<dim3(256 / 32, 128 / 32), tb, 0, stream>>>(W_attn, wt_attn, 256, 128);
  transpose_bf16_kernel<<<dim3(256 / 32, 256 / 32), tb, 0, stream>>>(W_out, wt_out, 256, 256);
  transpose_bf16_kernel<<<dim3(256 / 32, 1024 / 32), tb, 0, stream>>>(W_ffn1, wt_ffn1, 256, 1024);
  transpose_bf16_kernel<<<dim3(1024 / 32, 256 / 32), tb, 0, stream>>>(W_ffn2, wt_ffn2, 1024, 256);

  // 1. LN1 (+pos)
  ln_kernel<true><<<M, 256, 0, stream>>>(src, pos, ln1_g, ln1_b, src_n_bf, q_bf);

  const int MB = (M + 127) / 128;   // 208
  // 2. projections
  mgemm<0, true ><<<dim3(MB, 2), 256, 0, stream>>>(src_n_bf, wt_val, b_value, nullptr, v_bf, M, 256, 256);
  mgemm<0, false><<<dim3(MB, 2), 256, 0, stream>>>(q_bf, wt_off, b_off, nullptr, offb, M, 256, 256);
  mgemm<0, false><<<dim3(MB, 1), 256, 0, stream>>>(q_bf, wt_attn, b_attn, nullptr, awbuf, M, 128, 256);

  // 3. softmax + sampling
  msda_kernel<<<M / 4, 256, 0, stream>>>(v_bf, offb, awbuf, ref, attn_bf);

  // 4. out-proj + residual -> src1 (f32)
  mgemm<2, false><<<dim3(MB, 2), 256, 0, stream>>>(attn_bf, wt_out, b_out, src, src1, M, 256, 256);

  // 5. LN2 -> bf16
  ln_kernel<false><<<M, 256, 0, stream>>>(src1, nullptr, ln2_g, ln2_b, sn2_bf, nullptr);

  // 6. FFN
  mgemm<1, true ><<<dim3(MB, 8), 256, 0, stream>>>(sn2_bf, wt_ffn1, b_ffn1, nullptr, hid_bf, M, 1024, 256);
  mgemm<2, false><<<dim3(MB, 2), 256, 0, stream>>>(hid_bf, wt_ffn2, b_ffn2, src1, out, M, 256, 1024);
}

// Round 5
// 295.251 us; speedup vs baseline: 2.8068x; 1.3069x over previous
//
#include <hip/hip_runtime.h>
#include <hip/hip_bf16.h>

#define T_TOK   13294
#define BS_     2
#define M_ROWS  (BS_ * T_TOK)   // 26588
#define EMBED_  256
#define HID_    1024

typedef __attribute__((ext_vector_type(8))) short short8;
typedef __attribute__((ext_vector_type(4))) float f32x4;

__device__ __forceinline__ unsigned short f2bf(float f) {
  __hip_bfloat16 h = __float2bfloat16(f);
  return *reinterpret_cast<unsigned short*>(&h);
}
__device__ __forceinline__ float bf2f(unsigned short u) {
  unsigned int x = ((unsigned int)u) << 16;
  return __uint_as_float(x);
}

// ---------------------------------------------------------------------------
// Weight transpose + bf16 cast: W [K,N] f32 -> Wt [N,K] bf16
// ---------------------------------------------------------------------------
__global__ __launch_bounds__(256) void transpose_bf16_kernel(
    const float* __restrict__ W, unsigned short* __restrict__ Wt, int K, int N) {
  __shared__ float t[32][33];
  const int k0 = blockIdx.x * 32, n0 = blockIdx.y * 32;
  const int tx = threadIdx.x, ty = threadIdx.y;   // 32 x 8
  #pragma unroll
  for (int i = 0; i < 32; i += 8)
    t[ty + i][tx] = W[(size_t)(k0 + ty + i) * N + n0 + tx];
  __syncthreads();
  #pragma unroll
  for (int i = 0; i < 32; i += 8)
    Wt[(size_t)(n0 + ty + i) * K + k0 + tx] = f2bf(t[tx][ty + i]);
}

// ---------------------------------------------------------------------------
// LayerNorm -> bf16 (one block per row). ADDPOS: also q = ln(x)+pos (bf16)
// ---------------------------------------------------------------------------
template <bool ADDPOS>
__global__ __launch_bounds__(256) void ln_kernel(
    const float* __restrict__ x, const float* __restrict__ pos,
    const float* __restrict__ g, const float* __restrict__ bta,
    unsigned short* __restrict__ y, unsigned short* __restrict__ q) {
  const int r = blockIdx.x;
  const int tid = threadIdx.x;
  const size_t base = (size_t)r * 256 + tid;
  float v = x[base];

  float s = v;
  #pragma unroll
  for (int m = 32; m; m >>= 1) s += __shfl_xor(s, m, 64);
  __shared__ float red[4];
  const int wid = tid >> 6;
  if ((tid & 63) == 0) red[wid] = s;
  __syncthreads();
  const float mean = (red[0] + red[1] + red[2] + red[3]) * (1.0f / 256.0f);

  const float d = v - mean;
  float s2 = d * d;
  #pragma unroll
  for (int m = 32; m; m >>= 1) s2 += __shfl_xor(s2, m, 64);
  __syncthreads();
  if ((tid & 63) == 0) red[wid] = s2;
  __syncthreads();
  const float var = (red[0] + red[1] + red[2] + red[3]) * (1.0f / 256.0f);

  const float out = d * rsqrtf(var + 1e-5f) * g[tid] + bta[tid];
  y[base] = f2bf(out);
  if (ADDPOS) q[base] = f2bf(out + pos[base]);
}

// ---------------------------------------------------------------------------
// MFMA bf16 GEMM, 2-phase double-buffered LDS (T3 minimal recipe):
// issue next-tile global_load_lds BEFORE ds_read+MFMA of current tile;
// one drain barrier per K-step. C = A[M,K] @ Wt[N,K]^T + bias (+epilogue).
// 128x128 tile, BK=32, 256 threads (4 waves 2x2). 1D grid + XCD chunk swizzle.
// ---------------------------------------------------------------------------
template <int EPI, bool OUTBF>
__global__ __launch_bounds__(256) void mgemm(
    const unsigned short* __restrict__ A, const unsigned short* __restrict__ Wt,
    const float* __restrict__ bias, const float* __restrict__ R,
    void* __restrict__ Cv, int M, int N, int K, int nbx) {
  __shared__ unsigned short As[2][128 * 32];
  __shared__ unsigned short Bs[2][128 * 32];

  const int tid = threadIdx.x;
  const int lane = tid & 63;
  const int w = tid >> 6;
  const int wm = w >> 1, wn = w & 1;

  // XCD chunk swizzle (grid always divisible by 8 here)
  const int nwg = gridDim.x;
  const int bid = blockIdx.x;
  const int wgid = (bid & 7) * (nwg >> 3) + (bid >> 3);
  const int row0 = (wgid / (N >> 7)) * 128;   // N/128 col-blocks, row-major
  const int col0 = (wgid % (N >> 7)) * 128;
  (void)nbx;

  f32x4 acc[4][4] = {};

  const int frow = lane & 15;
  const int fk = (lane >> 4) * 8;

  // staging helper: 2 chunks each of 256 lanes x 16B for A and B tiles
  auto stage = [&](int buf, int k0) {
    #pragma unroll
    for (int i = 0; i < 2; ++i) {
      const int chunk = i * 256 + tid;     // 0..511
      const int rrow = chunk >> 2;         // 0..127
      const int kg = chunk & 3;
      int ga_row = row0 + rrow; if (ga_row >= M) ga_row = M - 1;  // clamp
      const unsigned short* gA = A + (size_t)ga_row * K + k0 + kg * 8;
      __builtin_amdgcn_global_load_lds(
          (const __attribute__((address_space(1))) void*)gA,
          (__attribute__((address_space(3))) void*)&As[buf][chunk * 8], 16, 0, 0);
      const unsigned short* gB = Wt + (size_t)(col0 + rrow) * K + k0 + kg * 8;
      __builtin_amdgcn_global_load_lds(
          (const __attribute__((address_space(1))) void*)gB,
          (__attribute__((address_space(3))) void*)&Bs[buf][chunk * 8], 16, 0, 0);
    }
  };

  stage(0, 0);
  __syncthreads();                 // drains vmcnt: buf0 ready
  int cur = 0;
  for (int k0 = 0; k0 < K; k0 += 32) {
    if (k0 + 32 < K) stage(cur ^ 1, k0 + 32);   // prefetch next (overlaps MFMA)

    short8 a[4], b[4];
    #pragma unroll
    for (int mi = 0; mi < 4; ++mi)
      a[mi] = *reinterpret_cast<const short8*>(&As[cur][(wm * 64 + mi * 16 + frow) * 32 + fk]);
    #pragma unroll
    for (int ni = 0; ni < 4; ++ni)
      b[ni] = *reinterpret_cast<const short8*>(&Bs[cur][(wn * 64 + ni * 16 + frow) * 32 + fk]);
    #pragma unroll
    for (int mi = 0; mi < 4; ++mi)
      #pragma unroll
      for (int ni = 0; ni < 4; ++ni)
        acc[mi][ni] = __builtin_amdgcn_mfma_f32_16x16x32_bf16(a[mi], b[ni], acc[mi][ni], 0, 0, 0);

    __syncthreads();               // drains prefetch (vmcnt 0) + lgkm
    cur ^= 1;
  }

  // epilogue: C/D layout col=lane&15, row=(lane>>4)*4+r
  const int cl = lane & 15;
  const int rb = (lane >> 4) * 4;
  #pragma unroll
  for (int ni = 0; ni < 4; ++ni) {
    const int gc = col0 + wn * 64 + ni * 16 + cl;
    const float bv = bias[gc];
    #pragma unroll
    for (int mi = 0; mi < 4; ++mi) {
      const int gr0 = row0 + wm * 64 + mi * 16 + rb;
      #pragma unroll
      for (int r = 0; r < 4; ++r) {
        const int gr = gr0 + r;
        if (gr >= M) continue;
        float val = acc[mi][ni][r] + bv;
        if (EPI == 1) val = fmaxf(val, 0.f);
        if (EPI == 2) val += R[(size_t)gr * N + gc];
        if (OUTBF) ((unsigned short*)Cv)[(size_t)gr * N + gc] = f2bf(val);
        else       ((float*)Cv)[(size_t)gr * N + gc] = val;
      }
    }
  }
}

// ---------------------------------------------------------------------------
// Fused softmax + deformable sampling — BRANCHLESS gathers.
// 4 tokens/block, 256 threads: (token t=tid>>6, head h, 4-channel group d4).
// ---------------------------------------------------------------------------
__global__ __launch_bounds__(256) void msda_kernel(
    const unsigned short* __restrict__ v, const float* __restrict__ offb,
    const float* __restrict__ awl, const float* __restrict__ ref,
    unsigned short* __restrict__ outb) {
  const int r0 = blockIdx.x * 4;
  const int tid = threadIdx.x;

  __shared__ float s_off[4 * 256];
  __shared__ float s_aw[4 * 128];
  __shared__ float s_ref[4 * 8];

  #pragma unroll
  for (int i = 0; i < 4; ++i)
    s_off[i * 256 + tid] = offb[(size_t)(r0 + i) * 256 + tid];
  if (tid < 32) s_ref[tid] = ref[(size_t)r0 * 8 + tid];

  // softmax: 32 (token,head) pairs, 8 threads each, 2 logits/thread
  {
    const int pair = tid >> 3;
    const int j = tid & 7;
    const int tok = pair >> 3, h = pair & 7;
    const size_t base = (size_t)(r0 + tok) * 128 + h * 16 + j * 2;
    const float l0 = awl[base], l1 = awl[base + 1];
    float mx = fmaxf(l0, l1);
    #pragma unroll
    for (int m = 1; m < 8; m <<= 1) mx = fmaxf(mx, __shfl_xor(mx, m, 64));
    const float e0 = expf(l0 - mx), e1 = expf(l1 - mx);
    float ss = e0 + e1;
    #pragma unroll
    for (int m = 1; m < 8; m <<= 1) ss += __shfl_xor(ss, m, 64);
    const float inv = 1.0f / ss;
    s_aw[tok * 128 + h * 16 + j * 2] = e0 * inv;
    s_aw[tok * 128 + h * 16 + j * 2 + 1] = e1 * inv;
  }
  __syncthreads();

  const int t = tid >> 6;
  const int lane = tid & 63;
  const int h = lane >> 3, d4 = lane & 7;
  const int r = r0 + t;
  const int b = r / T_TOK;

  const int HH[4] = {100, 50, 25, 13};
  const int WW[4] = {100, 50, 25, 13};
  const int SS[4] = {0, 10000, 12500, 13125};

  // per-thread base into v for this (batch, head, channel group)
  const unsigned short* vb = v + (size_t)b * T_TOK * 256 + h * 32 + d4 * 4;

  float acc0 = 0.f, acc1 = 0.f, acc2 = 0.f, acc3 = 0.f;
  #pragma unroll
  for (int l = 0; l < 4; ++l) {
    const float Wl = (float)WW[l], Hl = (float)HH[l];
    const float rx = s_ref[t * 8 + l * 2], ry = s_ref[t * 8 + l * 2 + 1];
    #pragma unroll
    for (int p = 0; p < 4; ++p) {
      const float ox = s_off[t * 256 + h * 32 + l * 8 + p * 2];
      const float oy = s_off[t * 256 + h * 32 + l * 8 + p * 2 + 1];
      const float x = rx * Wl + ox - 0.5f;
      const float y = ry * Hl + oy - 0.5f;
      const float x0f = floorf(x), y0f = floorf(y);
      const int x0 = (int)x0f, y0 = (int)y0f;
      const float wx1 = x - x0f, wy1 = y - y0f;
      const float wx0 = 1.f - wx1, wy0 = 1.f - wy1;
      const float aw = s_aw[t * 128 + h * 16 + l * 4 + p];

      // branchless 4-corner gather: clamped (always-valid) address,
      // weight zeroed when out-of-range -> no exec-mask divergence
      #pragma unroll
      for (int c = 0; c < 4; ++c) {
        const int xx = x0 + (c & 1);
        const int yy = y0 + (c >> 1);
        const bool valid = (xx >= 0) & (xx < WW[l]) & (yy >= 0) & (yy < HH[l]);
        const int xc = min(max(xx, 0), WW[l] - 1);
        const int yc = min(max(yy, 0), HH[l] - 1);
        float wgt = aw * ((c & 1) ? wx1 : wx0) * ((c >> 1) ? wy1 : wy0);
        wgt = valid ? wgt : 0.f;
        const uint2 u = *reinterpret_cast<const uint2*>(
            vb + ((size_t)(SS[l] + yc * WW[l] + xc)) * 256);
        acc0 = fmaf(wgt, bf2f((unsigned short)(u.x & 0xffff)), acc0);
        acc1 = fmaf(wgt, bf2f((unsigned short)(u.x >> 16)), acc1);
        acc2 = fmaf(wgt, bf2f((unsigned short)(u.y & 0xffff)), acc2);
        acc3 = fmaf(wgt, bf2f((unsigned short)(u.y >> 16)), acc3);
      }
    }
  }
  const size_t ob = (size_t)r * 256 + h * 32 + d4 * 4;
  ushort4 o;
  o.x = f2bf(acc0); o.y = f2bf(acc1); o.z = f2bf(acc2); o.w = f2bf(acc3);
  *reinterpret_cast<ushort4*>(&outb[ob]) = o;
}

// ---------------------------------------------------------------------------
// Host launcher
// ---------------------------------------------------------------------------
extern "C" void kernel_launch(void* const* d_in, const int* in_sizes, int n_in,
                              void* d_out, int out_size, void* d_ws, size_t ws_size,
                              hipStream_t stream) {
  const float* src     = (const float*)d_in[0];
  const float* pos     = (const float*)d_in[1];
  const float* ref     = (const float*)d_in[2];
  const float* ln1_g   = (const float*)d_in[5];
  const float* ln1_b   = (const float*)d_in[6];
  const float* ln2_g   = (const float*)d_in[7];
  const float* ln2_b   = (const float*)d_in[8];
  const float* W_value = (const float*)d_in[9];
  const float* b_value = (const float*)d_in[10];
  const float* W_off   = (const float*)d_in[11];
  const float* b_off   = (const float*)d_in[12];
  const float* W_attn  = (const float*)d_in[13];
  const float* b_attn  = (const float*)d_in[14];
  const float* W_out   = (const float*)d_in[15];
  const float* b_out   = (const float*)d_in[16];
  const float* W_ffn1  = (const float*)d_in[17];
  const float* b_ffn1  = (const float*)d_in[18];
  const float* W_ffn2  = (const float*)d_in[19];
  const float* b_ffn2  = (const float*)d_in[20];
  float* out = (float*)d_out;

  const int M = M_ROWS;
  const size_t n256 = (size_t)M * 256;

  // workspace layout
  unsigned short* src_n_bf = (unsigned short*)d_ws;
  unsigned short* q_bf     = src_n_bf + n256;
  unsigned short* v_bf     = q_bf + n256;
  unsigned short* attn_bf  = v_bf + n256;
  unsigned short* sn2_bf   = attn_bf + n256;
  unsigned short* hid_bf   = sn2_bf + n256;                  // M*1024
  float* offb  = (float*)(hid_bf + (size_t)M * 1024);
  float* awbuf = offb + n256;
  float* src1  = awbuf + (size_t)M * 128;
  unsigned short* wt_val  = (unsigned short*)(src1 + n256);
  unsigned short* wt_off  = wt_val + 256 * 256;
  unsigned short* wt_attn = wt_off + 256 * 256;
  unsigned short* wt_out  = wt_attn + 128 * 256;
  unsigned short* wt_ffn1 = wt_out + 256 * 256;
  unsigned short* wt_ffn2 = wt_ffn1 + 1024 * 256;

  const dim3 tb(32, 8);
  transpose_bf16_kernel<<<dim3(256 / 32, 256 / 32), tb, 0, stream>>>(W_value, wt_val, 256, 256);
  transpose_bf16_kernel<<<dim3(256 / 32, 256 / 32), tb, 0, stream>>>(W_off, wt_off, 256, 256);
  transpose_bf16_kernel<<<dim3(256 / 32, 128 / 32), tb, 0, stream>>>(W_attn, wt_attn, 256, 128);
  transpose_bf16_kernel<<<dim3(256 / 32, 256 / 32), tb, 0, stream>>>(W_out, wt_out, 256, 256);
  transpose_bf16_kernel<<<dim3(256 / 32, 1024 / 32), tb, 0, stream>>>(W_ffn1, wt_ffn1, 256, 1024);
  transpose_bf16_kernel<<<dim3(1024 / 32, 256 / 32), tb, 0, stream>>>(W_ffn2, wt_ffn2, 1024, 256);

  // 1. LN1 (+pos)
  ln_kernel<true><<<M, 256, 0, stream>>>(src, pos, ln1_g, ln1_b, src_n_bf, q_bf);

  const int MB = (M + 127) / 128;   // 208
  // 2. projections (1D grid = MB * N/128, row-major, XCD-swizzled inside)
  mgemm<0, true ><<<MB * 2, 256, 0, stream>>>(src_n_bf, wt_val, b_value, nullptr, v_bf, M, 256, 256, MB);
  mgemm<0, false><<<MB * 2, 256, 0, stream>>>(q_bf, wt_off, b_off, nullptr, offb, M, 256, 256, MB);
  mgemm<0, false><<<MB * 1, 256, 0, stream>>>(q_bf, wt_attn, b_attn, nullptr, awbuf, M, 128, 256, MB);

  // 3. softmax + sampling
  msda_kernel<<<M / 4, 256, 0, stream>>>(v_bf, offb, awbuf, ref, attn_bf);

  // 4. out-proj + residual -> src1 (f32)
  mgemm<2, false><<<MB * 2, 256, 0, stream>>>(attn_bf, wt_out, b_out, src, src1, M, 256, 256, MB);

  // 5. LN2 -> bf16
  ln_kernel<false><<<M, 256, 0, stream>>>(src1, nullptr, ln2_g, ln2_b, sn2_bf, nullptr);

  // 6. FFN
  mgemm<1, true ><<<MB * 8, 256, 0, stream>>>(sn2_bf, wt_ffn1, b_ffn1, nullptr, hid_bf, M, 1024, 256, MB);
  mgemm<2, false><<<MB * 2, 256, 0, stream>>>(hid_bf, wt_ffn2, b_ffn2, src1, out, M, 256, 1024, MB);
}

// Round 6
// 246.209 us; speedup vs baseline: 3.3658x; 1.1992x over previous
//
#include <hip/hip_runtime.h>
#include <hip/hip_bf16.h>

#define T_TOK   13294
#define BS_     2
#define M_ROWS  (BS_ * T_TOK)   // 26588
#define EMBED_  256
#define HID_    1024

typedef __attribute__((ext_vector_type(8))) short short8;
typedef __attribute__((ext_vector_type(4))) float f32x4;

__device__ __forceinline__ unsigned short f2bf(float f) {
  __hip_bfloat16 h = __float2bfloat16(f);
  return *reinterpret_cast<unsigned short*>(&h);
}
__device__ __forceinline__ float bf2f(unsigned short u) {
  unsigned int x = ((unsigned int)u) << 16;
  return __uint_as_float(x);
}

// ---------------------------------------------------------------------------
// Fused transpose+bf16 of all 6 weight matrices in one launch.
// 32x32 tiles; block -> matrix via static tile-range table.
// ---------------------------------------------------------------------------
__global__ __launch_bounds__(256) void transpose_all_kernel(
    const float* __restrict__ s0, const float* __restrict__ s1,
    const float* __restrict__ s2, const float* __restrict__ s3,
    const float* __restrict__ s4, const float* __restrict__ s5,
    unsigned short* __restrict__ d0, unsigned short* __restrict__ d1,
    unsigned short* __restrict__ d2, unsigned short* __restrict__ d3,
    unsigned short* __restrict__ d4, unsigned short* __restrict__ d5) {
  __shared__ float t[32][33];
  const int bid = blockIdx.x;
  const float* S; unsigned short* D; int K, N, t0;
  if      (bid <  64) { S = s0; D = d0; K = 256;  N = 256;  t0 = 0;   }
  else if (bid < 128) { S = s1; D = d1; K = 256;  N = 256;  t0 = 64;  }
  else if (bid < 160) { S = s2; D = d2; K = 256;  N = 128;  t0 = 128; }
  else if (bid < 224) { S = s3; D = d3; K = 256;  N = 256;  t0 = 160; }
  else if (bid < 480) { S = s4; D = d4; K = 256;  N = 1024; t0 = 224; }
  else                { S = s5; D = d5; K = 1024; N = 256;  t0 = 480; }
  const int tile = bid - t0;
  const int ntx = N >> 5;
  const int k0 = (tile / ntx) * 32, n0 = (tile % ntx) * 32;
  const int tx = threadIdx.x, ty = threadIdx.y;   // 32 x 8
  #pragma unroll
  for (int i = 0; i < 32; i += 8)
    t[ty + i][tx] = S[(size_t)(k0 + ty + i) * N + n0 + tx];
  __syncthreads();
  #pragma unroll
  for (int i = 0; i < 32; i += 8)
    D[(size_t)(n0 + ty + i) * K + k0 + tx] = f2bf(t[tx][ty + i]);
}

// ---------------------------------------------------------------------------
// LayerNorm -> bf16, 4 rows/block (1 wave/row, float4/lane, no LDS/barriers)
// ---------------------------------------------------------------------------
template <bool ADDPOS>
__global__ __launch_bounds__(256) void ln4_kernel(
    const float* __restrict__ x, const float* __restrict__ pos,
    const float* __restrict__ g, const float* __restrict__ bta,
    unsigned short* __restrict__ y, unsigned short* __restrict__ q) {
  const int wave = threadIdx.x >> 6, lane = threadIdx.x & 63;
  const int r = blockIdx.x * 4 + wave;
  const size_t base = (size_t)r * 256 + lane * 4;
  const float4 v = *reinterpret_cast<const float4*>(&x[base]);

  float s = v.x + v.y + v.z + v.w;
  #pragma unroll
  for (int m = 32; m; m >>= 1) s += __shfl_xor(s, m, 64);
  const float mean = s * (1.0f / 256.0f);

  const float dx = v.x - mean, dy = v.y - mean, dz = v.z - mean, dw = v.w - mean;
  float s2 = dx * dx + dy * dy + dz * dz + dw * dw;
  #pragma unroll
  for (int m = 32; m; m >>= 1) s2 += __shfl_xor(s2, m, 64);
  const float rinv = rsqrtf(s2 * (1.0f / 256.0f) + 1e-5f);

  const float4 gg = *reinterpret_cast<const float4*>(&g[lane * 4]);
  const float4 bb = *reinterpret_cast<const float4*>(&bta[lane * 4]);
  const float o0 = dx * rinv * gg.x + bb.x;
  const float o1 = dy * rinv * gg.y + bb.y;
  const float o2 = dz * rinv * gg.z + bb.z;
  const float o3 = dw * rinv * gg.w + bb.w;
  ushort4 yo; yo.x = f2bf(o0); yo.y = f2bf(o1); yo.z = f2bf(o2); yo.w = f2bf(o3);
  *reinterpret_cast<ushort4*>(&y[base]) = yo;
  if (ADDPOS) {
    const float4 pp = *reinterpret_cast<const float4*>(&pos[base]);
    ushort4 qo;
    qo.x = f2bf(o0 + pp.x); qo.y = f2bf(o1 + pp.y);
    qo.z = f2bf(o2 + pp.z); qo.w = f2bf(o3 + pp.w);
    *reinterpret_cast<ushort4*>(&q[base]) = qo;
  }
}

// ---------------------------------------------------------------------------
// MFMA bf16 GEMM, 3-deep LDS pipeline with counted vmcnt (never drains to 0
// mid-loop) + k-group XOR swizzle (8-way ds_read_b128 bank conflict -> 2-way).
// C = A[M,K] @ Wt[N,K]^T + bias.
// EPI: 0=bias, 1=bias+relu, 2=bias+residual R, 3=split off/attn outputs.
// 128x128 tile, BK=32, 256 threads (4 waves 2x2). 1D grid + XCD chunk swizzle.
// ---------------------------------------------------------------------------
template <int EPI, bool OUTBF>
__global__ __launch_bounds__(256) void mgemm(
    const unsigned short* __restrict__ A, const unsigned short* __restrict__ Wt,
    const float* __restrict__ bias, const float* __restrict__ R,
    void* __restrict__ Cv, void* __restrict__ Cv2, int M, int N, int K) {
  __shared__ unsigned short As[3][128 * 32];
  __shared__ unsigned short Bs[3][128 * 32];

  const int tid = threadIdx.x;
  const int lane = tid & 63;
  const int w = tid >> 6;
  const int wm = w >> 1, wn = w & 1;

  // XCD chunk swizzle (grid always divisible by 8 here)
  const int nwg = gridDim.x;
  const int bid = blockIdx.x;
  const int wgid = (bid & 7) * (nwg >> 3) + (bid >> 3);
  const int NT = N >> 7;
  const int row0 = (wgid / NT) * 128;
  const int col0 = (wgid % NT) * 128;

  f32x4 acc[4][4] = {};

  const int frow = lane & 15;
  const int fkg  = lane >> 4;                  // k-group 0..3
  const int fke  = ((fkg ^ ((frow >> 1) & 3)) * 8);  // swizzled elem offset
  const int nt = K >> 5;

  // stage: cooperative 128x32 A-tile + B-tile; source k-group pre-swizzled
  // so LDS dest stays linear (global_load_lds requirement, rule 21).
  auto stage = [&](unsigned short* Ad, unsigned short* Bd, int k0) {
    #pragma unroll
    for (int i = 0; i < 2; ++i) {
      const int chunk = i * 256 + tid;     // 0..511
      const int rrow = chunk >> 2;         // 0..127
      const int kg = chunk & 3;
      const int kgs = kg ^ ((rrow >> 1) & 3);
      int ga_row = row0 + rrow; if (ga_row >= M) ga_row = M - 1;  // clamp
      const unsigned short* gA = A + (size_t)ga_row * K + k0 + kgs * 8;
      __builtin_amdgcn_global_load_lds(
          (const __attribute__((address_space(1))) void*)gA,
          (__attribute__((address_space(3))) void*)(Ad + chunk * 8), 16, 0, 0);
      const unsigned short* gB = Wt + (size_t)(col0 + rrow) * K + k0 + kgs * 8;
      __builtin_amdgcn_global_load_lds(
          (const __attribute__((address_space(1))) void*)gB,
          (__attribute__((address_space(3))) void*)(Bd + chunk * 8), 16, 0, 0);
    }
  };

  stage(&As[0][0], &Bs[0][0], 0);
  stage(&As[1][0], &Bs[1][0], 32);
  asm volatile("s_waitcnt vmcnt(4)" ::: "memory");   // tile0 landed, tile1 in flight
  __builtin_amdgcn_s_barrier();
  asm volatile("" ::: "memory");

  int cur = 0;
  for (int t = 0; t < nt; ++t) {
    if (t + 2 < nt) {
      const int s2 = (cur >= 1) ? cur - 1 : cur + 2;   // (cur+2)%3
      stage(&As[s2][0], &Bs[s2][0], (t + 2) << 5);
    }

    short8 a[4], b[4];
    #pragma unroll
    for (int mi = 0; mi < 4; ++mi)
      a[mi] = *reinterpret_cast<const short8*>(&As[cur][(wm * 64 + mi * 16 + frow) * 32 + fke]);
    #pragma unroll
    for (int ni = 0; ni < 4; ++ni)
      b[ni] = *reinterpret_cast<const short8*>(&Bs[cur][(wn * 64 + ni * 16 + frow) * 32 + fke]);
    #pragma unroll
    for (int mi = 0; mi < 4; ++mi)
      #pragma unroll
      for (int ni = 0; ni < 4; ++ni)
        acc[mi][ni] = __builtin_amdgcn_mfma_f32_16x16x32_bf16(a[mi], b[ni], acc[mi][ni], 0, 0, 0);

    if (t + 1 < nt) {
      // next tile's loads were issued >=1 full compute phase ago; keep the
      // newest prefetch (4 loads) in flight across the barrier (T4).
      if (t + 2 < nt) asm volatile("s_waitcnt vmcnt(4)" ::: "memory");
      else            asm volatile("s_waitcnt vmcnt(0)" ::: "memory");
      __builtin_amdgcn_s_barrier();
      asm volatile("" ::: "memory");
      cur = (cur >= 2) ? 0 : cur + 1;
    }
  }

  // epilogue: C/D layout col=lane&15, row=(lane>>4)*4+r
  const int cl = lane & 15;
  const int rb = (lane >> 4) * 4;
  #pragma unroll
  for (int ni = 0; ni < 4; ++ni) {
    const int gc = col0 + wn * 64 + ni * 16 + cl;
    float bv;
    if (EPI == 3) bv = (gc < 256) ? bias[gc] : R[gc - 256];
    else          bv = bias[gc];
    #pragma unroll
    for (int mi = 0; mi < 4; ++mi) {
      const int gr0 = row0 + wm * 64 + mi * 16 + rb;
      #pragma unroll
      for (int r = 0; r < 4; ++r) {
        const int gr = gr0 + r;
        if (gr >= M) continue;
        float val = acc[mi][ni][r] + bv;
        if (EPI == 1) val = fmaxf(val, 0.f);
        if (EPI == 2) val += R[(size_t)gr * N + gc];
        if (EPI == 3) {
          if (gc < 256) ((float*)Cv )[(size_t)gr * 256 + gc] = val;
          else          ((float*)Cv2)[(size_t)gr * 128 + gc - 256] = val;
        } else if (OUTBF) {
          ((unsigned short*)Cv)[(size_t)gr * N + gc] = f2bf(val);
        } else {
          ((float*)Cv)[(size_t)gr * N + gc] = val;
        }
      }
    }
  }
}

// ---------------------------------------------------------------------------
// Fused softmax + deformable sampling, LDS-precomputed (weight, idx) pairs:
// coordinate math done ONCE per (tok,head,point,corner) instead of 8x.
// 4 tokens/block, 256 threads: (token t=tid>>6, head h, 4-channel group d4).
// ---------------------------------------------------------------------------
__global__ __launch_bounds__(256) void msda_kernel(
    const unsigned short* __restrict__ v, const float* __restrict__ offb,
    const float* __restrict__ awl, const float* __restrict__ ref,
    unsigned short* __restrict__ outb) {
  const int r0 = blockIdx.x * 4;
  const int tid = threadIdx.x;

  __shared__ float s_off[4 * 256];
  __shared__ float s_aw[4 * 128];
  __shared__ float s_ref[32];
  __shared__ float2 s_wi[2048];   // [tok][h][pt][corner] = (weight, byte-idx)

  #pragma unroll
  for (int i = 0; i < 4; ++i)
    s_off[i * 256 + tid] = offb[(size_t)(r0 + i) * 256 + tid];
  if (tid < 32) s_ref[tid] = ref[(size_t)r0 * 8 + tid];

  // softmax: 32 (token,head) pairs, 8 threads each, 2 logits/thread
  {
    const int pair = tid >> 3;
    const int j = tid & 7;
    const int tok = pair >> 3, h = pair & 7;
    const size_t base = (size_t)(r0 + tok) * 128 + h * 16 + j * 2;
    const float l0 = awl[base], l1 = awl[base + 1];
    float mx = fmaxf(l0, l1);
    #pragma unroll
    for (int m = 1; m < 8; m <<= 1) mx = fmaxf(mx, __shfl_xor(mx, m, 64));
    const float e0 = expf(l0 - mx), e1 = expf(l1 - mx);
    float ss = e0 + e1;
    #pragma unroll
    for (int m = 1; m < 8; m <<= 1) ss += __shfl_xor(ss, m, 64);
    const float inv = 1.0f / ss;
    s_aw[tok * 128 + h * 16 + j * 2] = e0 * inv;
    s_aw[tok * 128 + h * 16 + j * 2 + 1] = e1 * inv;
  }
  __syncthreads();

  const int HH[4] = {100, 50, 25, 13};
  const int WW[4] = {100, 50, 25, 13};
  const int SS[4] = {0, 10000, 12500, 13125};

  // phase 2: (weight, byte-offset) per corner, 2 points/thread (512 points)
  #pragma unroll
  for (int pp = 0; pp < 2; ++pp) {
    const int pi = tid * 2 + pp;
    const int tok = pi >> 7, h = (pi >> 4) & 7, pt = pi & 15;
    const int l = pt >> 2, p = pt & 3;
    const float Wl = (float)WW[l], Hl = (float)HH[l];
    const float ox = s_off[tok * 256 + h * 32 + l * 8 + p * 2];
    const float oy = s_off[tok * 256 + h * 32 + l * 8 + p * 2 + 1];
    const float rx = s_ref[tok * 8 + l * 2], ry = s_ref[tok * 8 + l * 2 + 1];
    const float aw = s_aw[tok * 128 + h * 16 + l * 4 + p];
    const float x = rx * Wl + ox - 0.5f;
    const float y = ry * Hl + oy - 0.5f;
    const float x0f = floorf(x), y0f = floorf(y);
    const int x0 = (int)x0f, y0 = (int)y0f;
    const float wx1 = x - x0f, wy1 = y - y0f;
    const float wx0 = 1.f - wx1, wy0 = 1.f - wy1;
    #pragma unroll
    for (int c = 0; c < 4; ++c) {
      const int xx = x0 + (c & 1), yy = y0 + (c >> 1);
      const bool valid = (xx >= 0) & (xx < WW[l]) & (yy >= 0) & (yy < HH[l]);
      const int xc = min(max(xx, 0), WW[l] - 1);
      const int yc = min(max(yy, 0), HH[l] - 1);
      float wgt = aw * ((c & 1) ? wx1 : wx0) * ((c >> 1) ? wy1 : wy0);
      wgt = valid ? wgt : 0.f;
      const int idxb = (SS[l] + yc * WW[l] + xc) * 512;  // byte offset (256 bf16/row)
      s_wi[pi * 4 + c] = make_float2(wgt, __int_as_float(idxb));
    }
  }
  __syncthreads();

  // phase 3: gather loop — ds_read_b64 (8-lane broadcast) + dwordx2 + 4 fma
  const int t = tid >> 6;
  const int lane = tid & 63;
  const int h = lane >> 3, d4 = lane & 7;
  const int r = r0 + t;
  const int b = r / T_TOK;
  const char* vb = (const char*)(v + (size_t)b * T_TOK * 256 + h * 32 + d4 * 4);
  const int e0 = (t * 8 + h) * 64;

  float acc0 = 0.f, acc1 = 0.f, acc2 = 0.f, acc3 = 0.f;
  #pragma unroll 8
  for (int j = 0; j < 64; ++j) {
    const float2 wi = s_wi[e0 + j];
    const float wgt = wi.x;
    const int idxb = __float_as_int(wi.y);
    const uint2 u = *reinterpret_cast<const uint2*>(vb + idxb);
    acc0 = fmaf(wgt, bf2f((unsigned short)(u.x & 0xffff)), acc0);
    acc1 = fmaf(wgt, bf2f((unsigned short)(u.x >> 16)), acc1);
    acc2 = fmaf(wgt, bf2f((unsigned short)(u.y & 0xffff)), acc2);
    acc3 = fmaf(wgt, bf2f((unsigned short)(u.y >> 16)), acc3);
  }
  const size_t ob = (size_t)r * 256 + h * 32 + d4 * 4;
  ushort4 o;
  o.x = f2bf(acc0); o.y = f2bf(acc1); o.z = f2bf(acc2); o.w = f2bf(acc3);
  *reinterpret_cast<ushort4*>(&outb[ob]) = o;
}

// ---------------------------------------------------------------------------
// Host launcher
// ---------------------------------------------------------------------------
extern "C" void kernel_launch(void* const* d_in, const int* in_sizes, int n_in,
                              void* d_out, int out_size, void* d_ws, size_t ws_size,
                              hipStream_t stream) {
  const float* src     = (const float*)d_in[0];
  const float* pos     = (const float*)d_in[1];
  const float* ref     = (const float*)d_in[2];
  const float* ln1_g   = (const float*)d_in[5];
  const float* ln1_b   = (const float*)d_in[6];
  const float* ln2_g   = (const float*)d_in[7];
  const float* ln2_b   = (const float*)d_in[8];
  const float* W_value = (const float*)d_in[9];
  const float* b_value = (const float*)d_in[10];
  const float* W_off   = (const float*)d_in[11];
  const float* b_off   = (const float*)d_in[12];
  const float* W_attn  = (const float*)d_in[13];
  const float* b_attn  = (const float*)d_in[14];
  const float* W_out   = (const float*)d_in[15];
  const float* b_out   = (const float*)d_in[16];
  const float* W_ffn1  = (const float*)d_in[17];
  const float* b_ffn1  = (const float*)d_in[18];
  const float* W_ffn2  = (const float*)d_in[19];
  const float* b_ffn2  = (const float*)d_in[20];
  float* out = (float*)d_out;

  const int M = M_ROWS;
  const size_t n256 = (size_t)M * 256;

  // workspace layout
  unsigned short* src_n_bf = (unsigned short*)d_ws;
  unsigned short* q_bf     = src_n_bf + n256;
  unsigned short* v_bf     = q_bf + n256;
  unsigned short* attn_bf  = v_bf + n256;
  unsigned short* sn2_bf   = attn_bf + n256;
  unsigned short* hid_bf   = sn2_bf + n256;                  // M*1024
  float* offb  = (float*)(hid_bf + (size_t)M * 1024);
  float* awbuf = offb + n256;
  float* src1  = awbuf + (size_t)M * 128;
  unsigned short* wt_val     = (unsigned short*)(src1 + n256);
  unsigned short* wt_offattn = wt_val + 256 * 256;            // [384,256]
  unsigned short* wt_out     = wt_offattn + 384 * 256;
  unsigned short* wt_ffn1    = wt_out + 256 * 256;
  unsigned short* wt_ffn2    = wt_ffn1 + 1024 * 256;

  // 0. all weight transposes in one launch (736 tiles)
  transpose_all_kernel<<<736, dim3(32, 8), 0, stream>>>(
      W_value, W_off, W_attn, W_out, W_ffn1, W_ffn2,
      wt_val, wt_offattn, wt_offattn + 256 * 256, wt_out, wt_ffn1, wt_ffn2);

  // 1. LN1 (+pos)
  ln4_kernel<true><<<M / 4, 256, 0, stream>>>(src, pos, ln1_g, ln1_b, src_n_bf, q_bf);

  const int MB = (M + 127) / 128;   // 208
  // 2. value proj; fused off+attn proj (N=384, split outputs)
  mgemm<0, true ><<<MB * 2, 256, 0, stream>>>(src_n_bf, wt_val, b_value, nullptr,
                                              v_bf, nullptr, M, 256, 256);
  mgemm<3, false><<<MB * 3, 256, 0, stream>>>(q_bf, wt_offattn, b_off, b_attn,
                                              offb, awbuf, M, 384, 256);

  // 3. softmax + sampling
  msda_kernel<<<M / 4, 256, 0, stream>>>(v_bf, offb, awbuf, ref, attn_bf);

  // 4. out-proj + residual -> src1 (f32)
  mgemm<2, false><<<MB * 2, 256, 0, stream>>>(attn_bf, wt_out, b_out, src,
                                              src1, nullptr, M, 256, 256);

  // 5. LN2 -> bf16
  ln4_kernel<false><<<M / 4, 256, 0, stream>>>(src1, nullptr, ln2_g, ln2_b, sn2_bf, nullptr);

  // 6. FFN
  mgemm<1, true ><<<MB * 8, 256, 0, stream>>>(sn2_bf, wt_ffn1, b_ffn1, nullptr,
                                              hid_bf, nullptr, M, 1024, 256);
  mgemm<2, false><<<MB * 2, 256, 0, stream>>>(hid_bf, wt_ffn2, b_ffn2, src1,
                                              out, nullptr, M, 256, 1024);
}